// Round 1
// baseline (19567.682 us; speedup 1.0000x reference)
//
#include <hip/hip_runtime.h>
#include <hip/hip_bf16.h>

// Problem dims
#define TSTEPS 64
#define NB     512
#define DIN    556   // 300 + 128 + 128

__device__ __forceinline__ float sigmoidf_(float x) {
  return 1.0f / (1.0f + __expf(-x));
}
__device__ __forceinline__ float tanhf_(float x) {
  x = fminf(fmaxf(x, -15.0f), 15.0f);
  float e = __expf(2.0f * x);
  return (e - 1.0f) / (e + 1.0f);
}
__device__ __forceinline__ float4 load4g(const float* p, int k, int K) {
  if (k + 3 < K) return *(const float4*)(p + k);
  float4 v;
  v.x = (k + 0 < K) ? p[k + 0] : 0.0f;
  v.y = (k + 1 < K) ? p[k + 1] : 0.0f;
  v.z = (k + 2 < K) ? p[k + 2] : 0.0f;
  v.w = (k + 3 < K) ? p[k + 3] : 0.0f;
  return v;
}

// ---------------------------------------------------------------- zero init
__global__ __launch_bounds__(256) void zero_kernel(float4* p, int n4) {
  int i = blockIdx.x * 256 + threadIdx.x;
  if (i < n4) p[i] = make_float4(0.f, 0.f, 0.f, 0.f);
}

// ------------------------------------------------- fused LSTM gates + cell
// Grid: (8 m-tiles of 64, 16 j-tiles of 32 over the 512 combined hidden).
// Each block computes all 4 gates for its (m,j) tile and applies the cell
// update in the epilogue. h double-buffered (h_in read by ALL j-blocks).
__global__ __launch_bounds__(256) void gates_cell_kernel(
    const float* __restrict__ x_t,  // NB x 556 (this timestep)
    const float* __restrict__ h_in_l, const float* __restrict__ h_in_a,
    const float* __restrict__ h_in_v,
    float* __restrict__ h_out_l, float* __restrict__ h_out_a,
    float* __restrict__ h_out_v,
    float* __restrict__ c_l, float* __restrict__ c_a, float* __restrict__ c_v,
    const float* __restrict__ Wih_l, const float* __restrict__ Whh_l,
    const float* __restrict__ bih_l, const float* __restrict__ bhh_l,
    const float* __restrict__ Wih_a, const float* __restrict__ Whh_a,
    const float* __restrict__ bih_a, const float* __restrict__ bhh_a,
    const float* __restrict__ Wih_v, const float* __restrict__ Whh_v,
    const float* __restrict__ bih_v, const float* __restrict__ bhh_v,
    float* __restrict__ cstar)      // NB x 1024
{
  __shared__ float As[16][64];
  __shared__ float Ws[4][16][32];

  const int tid = threadIdx.x;
  const int m0  = blockIdx.x * 64;
  const int j0  = blockIdx.y * 32;   // within combined 512 hidden

  const float *Wih, *Whh, *bih, *bhh, *h_in;
  float *h_out, *cbuf;
  int xoff, K1, Hm, jm, oldbase;
  if (j0 < 256) {
    Wih = Wih_l; Whh = Whh_l; bih = bih_l; bhh = bhh_l;
    h_in = h_in_l; h_out = h_out_l; cbuf = c_l;
    xoff = 0; K1 = 300; Hm = 256; jm = j0; oldbase = 0;
  } else if (j0 < 384) {
    Wih = Wih_a; Whh = Whh_a; bih = bih_a; bhh = bhh_a;
    h_in = h_in_a; h_out = h_out_a; cbuf = c_a;
    xoff = 300; K1 = 128; Hm = 128; jm = j0 - 256; oldbase = 256;
  } else {
    Wih = Wih_v; Whh = Whh_v; bih = bih_v; bhh = bhh_v;
    h_in = h_in_v; h_out = h_out_v; cbuf = c_v;
    xoff = 428; K1 = 128; Hm = 128; jm = j0 - 384; oldbase = 384;
  }

  float acc[4][4][2];
  #pragma unroll
  for (int g = 0; g < 4; g++)
    #pragma unroll
    for (int i = 0; i < 4; i++) { acc[g][i][0] = 0.f; acc[g][i][1] = 0.f; }

  const int tx = tid & 15;   // 2 j each
  const int ty = tid >> 4;   // 4 m each
  const int alr = tid >> 2, alk = (tid & 3) << 2;

  for (int ph = 0; ph < 2; ph++) {
    const float* Abase; const float* Wb;
    int lda, K, wld;
    if (ph == 0) { Abase = x_t + xoff; lda = DIN; K = K1; Wb = Wih; wld = K1; }
    else         { Abase = h_in;       lda = Hm;  K = Hm; Wb = Whh; wld = Hm; }

    for (int k0 = 0; k0 < K; k0 += 16) {
      // A tile: 64 rows x 16 k
      {
        const float* src = Abase + (size_t)(m0 + alr) * lda;
        float4 v = load4g(src, k0 + alk, K);
        As[alk + 0][alr] = v.x; As[alk + 1][alr] = v.y;
        As[alk + 2][alr] = v.z; As[alk + 3][alr] = v.w;
      }
      // W tiles: 4 gates x 32 rows x 16 k = 512 float4, 2 per thread
      #pragma unroll
      for (int u = 0; u < 2; u++) {
        int idx = tid * 2 + u;
        int g = idx >> 7;
        int rem = idx & 127;
        int jr = rem >> 2;
        int k4 = (rem & 3) << 2;
        const float* src = Wb + (size_t)(g * Hm + jm + jr) * wld;
        float4 v = load4g(src, k0 + k4, K);
        Ws[g][k4 + 0][jr] = v.x; Ws[g][k4 + 1][jr] = v.y;
        Ws[g][k4 + 2][jr] = v.z; Ws[g][k4 + 3][jr] = v.w;
      }
      __syncthreads();
      #pragma unroll
      for (int kk = 0; kk < 16; kk++) {
        float4 a = *(const float4*)&As[kk][ty * 4];
        #pragma unroll
        for (int g = 0; g < 4; g++) {
          float2 w = *(const float2*)&Ws[g][kk][tx * 2];
          acc[g][0][0] += a.x * w.x; acc[g][0][1] += a.x * w.y;
          acc[g][1][0] += a.y * w.x; acc[g][1][1] += a.y * w.y;
          acc[g][2][0] += a.z * w.x; acc[g][2][1] += a.z * w.y;
          acc[g][3][0] += a.w * w.x; acc[g][3][1] += a.w * w.y;
        }
      }
      __syncthreads();
    }
  }

  // epilogue: LSTM cell update
  #pragma unroll
  for (int i = 0; i < 4; i++) {
    int m = m0 + ty * 4 + i;
    #pragma unroll
    for (int j = 0; j < 2; j++) {
      int jj = jm + tx * 2 + j;  // within modality
      float gi = acc[0][i][j] + bih[0 * Hm + jj] + bhh[0 * Hm + jj];
      float gf = acc[1][i][j] + bih[1 * Hm + jj] + bhh[1 * Hm + jj];
      float gg = acc[2][i][j] + bih[2 * Hm + jj] + bhh[2 * Hm + jj];
      float go = acc[3][i][j] + bih[3 * Hm + jj] + bhh[3 * Hm + jj];
      float c_old = cbuf[(size_t)m * Hm + jj];
      float c2 = sigmoidf_(gf) * c_old + sigmoidf_(gi) * tanhf_(gg);
      float h2 = sigmoidf_(go) * tanhf_(c2);
      cbuf[(size_t)m * Hm + jj] = c2;
      h_out[(size_t)m * Hm + jj] = h2;
      cstar[(size_t)m * 1024 + oldbase + jj] = c_old;
      cstar[(size_t)m * 1024 + 512 + oldbase + jj] = c2;
    }
  }
}

// ---------------------------------------------------- generic C = act(A W^T + b)
// A: M x lda (rows at least K valid), W: J x ldw (ldw == K), C: M x ldc.
// Grid: (M/64, J/64). K must be a multiple of 16.
__global__ __launch_bounds__(256) void lin_kernel(
    const float* __restrict__ A, int lda,
    const float* __restrict__ W, int ldw,
    const float* __restrict__ bias,
    float* __restrict__ C, int ldc,
    int K, int act)   // act: 0 none, 1 relu
{
  __shared__ float As[16][64];
  __shared__ float Ws[16][64];
  const int tid = threadIdx.x;
  const int tx = tid & 15, ty = tid >> 4;
  const int m0 = blockIdx.x * 64, j0 = blockIdx.y * 64;
  const int lr = tid >> 2, lk = (tid & 3) << 2;

  float acc[4][4];
  #pragma unroll
  for (int i = 0; i < 4; i++)
    #pragma unroll
    for (int j = 0; j < 4; j++) acc[i][j] = 0.f;

  const float* Arow = A + (size_t)(m0 + lr) * lda;
  const float* Wrow = W + (size_t)(j0 + lr) * ldw;

  for (int k0 = 0; k0 < K; k0 += 16) {
    float4 av = *(const float4*)(Arow + k0 + lk);
    float4 wv = *(const float4*)(Wrow + k0 + lk);
    As[lk + 0][lr] = av.x; As[lk + 1][lr] = av.y;
    As[lk + 2][lr] = av.z; As[lk + 3][lr] = av.w;
    Ws[lk + 0][lr] = wv.x; Ws[lk + 1][lr] = wv.y;
    Ws[lk + 2][lr] = wv.z; Ws[lk + 3][lr] = wv.w;
    __syncthreads();
    #pragma unroll
    for (int kk = 0; kk < 16; kk++) {
      float4 a = *(const float4*)&As[kk][ty * 4];
      float4 b = *(const float4*)&Ws[kk][tx * 4];
      acc[0][0] += a.x * b.x; acc[0][1] += a.x * b.y; acc[0][2] += a.x * b.z; acc[0][3] += a.x * b.w;
      acc[1][0] += a.y * b.x; acc[1][1] += a.y * b.y; acc[1][2] += a.y * b.z; acc[1][3] += a.y * b.w;
      acc[2][0] += a.z * b.x; acc[2][1] += a.z * b.y; acc[2][2] += a.z * b.z; acc[2][3] += a.z * b.w;
      acc[3][0] += a.w * b.x; acc[3][1] += a.w * b.y; acc[3][2] += a.w * b.z; acc[3][3] += a.w * b.w;
    }
    __syncthreads();
  }
  #pragma unroll
  for (int i = 0; i < 4; i++) {
    int m = m0 + ty * 4 + i;
    #pragma unroll
    for (int j = 0; j < 4; j++) {
      int jj = j0 + tx * 4 + j;
      float v = acc[i][j] + bias[jj];
      if (act == 1) v = fmaxf(v, 0.f);
      C[(size_t)m * ldc + jj] = v;
    }
  }
}

// ---------------------------------------- softmax over 1024 + attended = att*cStar
__global__ __launch_bounds__(256) void softmax_attend_kernel(
    const float* __restrict__ logits, const float* __restrict__ cstar,
    float* __restrict__ attd)
{
  __shared__ float red[256];
  const int n = blockIdx.x, tid = threadIdx.x;
  float4 v = *(const float4*)(logits + (size_t)n * 1024 + tid * 4);
  float mx = fmaxf(fmaxf(v.x, v.y), fmaxf(v.z, v.w));
  red[tid] = mx; __syncthreads();
  for (int s = 128; s > 0; s >>= 1) {
    if (tid < s) red[tid] = fmaxf(red[tid], red[tid + s]);
    __syncthreads();
  }
  mx = red[0]; __syncthreads();
  float e0 = __expf(v.x - mx), e1 = __expf(v.y - mx);
  float e2 = __expf(v.z - mx), e3 = __expf(v.w - mx);
  red[tid] = e0 + e1 + e2 + e3; __syncthreads();
  for (int s = 128; s > 0; s >>= 1) {
    if (tid < s) red[tid] += red[tid + s];
    __syncthreads();
  }
  float inv = 1.0f / red[0];
  float4 cs = *(const float4*)(cstar + (size_t)n * 1024 + tid * 4);
  float4 o;
  o.x = e0 * inv * cs.x; o.y = e1 * inv * cs.y;
  o.z = e2 * inv * cs.z; o.w = e3 * inv * cs.w;
  *(float4*)(attd + (size_t)n * 1024 + tid * 4) = o;
}

// ------------------------- merged z2|zg1|zg2 = relu([attended|mem] @ W^T + b)
// Output NB x 1536 (cols 0-511: att2_w1 K=1024; 512-1023: g1_w1 K=1280;
// 1024-1535: g2_w1 K=1280). Grid (8, 24).
__global__ __launch_bounds__(256) void z3_kernel(
    const float* __restrict__ attd,   // NB x 1024
    const float* __restrict__ memb,   // NB x 256
    const float* __restrict__ att2_w1, const float* __restrict__ att2_b1,
    const float* __restrict__ g1_w1,  const float* __restrict__ g1_b1,
    const float* __restrict__ g2_w1,  const float* __restrict__ g2_b1,
    float* __restrict__ z3)           // NB x 1536
{
  __shared__ float As[16][64];
  __shared__ float Ws[16][64];
  const int tid = threadIdx.x;
  const int tx = tid & 15, ty = tid >> 4;
  const int m0 = blockIdx.x * 64, j0 = blockIdx.y * 64;
  const int lr = tid >> 2, lk = (tid & 3) << 2;

  const float* W; const float* b; int K, jr0;
  if (j0 < 512)       { W = att2_w1; b = att2_b1; K = 1024; jr0 = j0; }
  else if (j0 < 1024) { W = g1_w1;  b = g1_b1;  K = 1280; jr0 = j0 - 512; }
  else                { W = g2_w1;  b = g2_b1;  K = 1280; jr0 = j0 - 1024; }

  float acc[4][4];
  #pragma unroll
  for (int i = 0; i < 4; i++)
    #pragma unroll
    for (int j = 0; j < 4; j++) acc[i][j] = 0.f;

  const float* Wrow = W + (size_t)(jr0 + lr) * K;
  const float* At = attd + (size_t)(m0 + lr) * 1024;
  const float* Mr = memb + (size_t)(m0 + lr) * 256;

  for (int k0 = 0; k0 < K; k0 += 16) {
    int k = k0 + lk;
    float4 av = (k < 1024) ? *(const float4*)(At + k)
                           : *(const float4*)(Mr + (k - 1024));
    float4 wv = *(const float4*)(Wrow + k);
    As[lk + 0][lr] = av.x; As[lk + 1][lr] = av.y;
    As[lk + 2][lr] = av.z; As[lk + 3][lr] = av.w;
    Ws[lk + 0][lr] = wv.x; Ws[lk + 1][lr] = wv.y;
    Ws[lk + 2][lr] = wv.z; Ws[lk + 3][lr] = wv.w;
    __syncthreads();
    #pragma unroll
    for (int kk = 0; kk < 16; kk++) {
      float4 a = *(const float4*)&As[kk][ty * 4];
      float4 b4 = *(const float4*)&Ws[kk][tx * 4];
      acc[0][0] += a.x * b4.x; acc[0][1] += a.x * b4.y; acc[0][2] += a.x * b4.z; acc[0][3] += a.x * b4.w;
      acc[1][0] += a.y * b4.x; acc[1][1] += a.y * b4.y; acc[1][2] += a.y * b4.z; acc[1][3] += a.y * b4.w;
      acc[2][0] += a.z * b4.x; acc[2][1] += a.z * b4.y; acc[2][2] += a.z * b4.z; acc[2][3] += a.z * b4.w;
      acc[3][0] += a.w * b4.x; acc[3][1] += a.w * b4.y; acc[3][2] += a.w * b4.z; acc[3][3] += a.w * b4.w;
    }
    __syncthreads();
  }
  #pragma unroll
  for (int i = 0; i < 4; i++) {
    int m = m0 + ty * 4 + i;
    #pragma unroll
    for (int j = 0; j < 4; j++) {
      int jl = tx * 4 + j;
      float v = fmaxf(acc[i][j] + b[jr0 + jl], 0.f);
      z3[(size_t)m * 1536 + j0 + jl] = v;
    }
  }
}

// ------------- merged cHat / gamma1 / gamma2 GEMMs + in-place mem update
// All three K=512, output NB x 256. Grid (8, 4).
__global__ __launch_bounds__(256) void gmem_kernel(
    const float* __restrict__ z3,     // NB x 1536 (z2|zg1|zg2)
    const float* __restrict__ att2_w2, const float* __restrict__ att2_b2,
    const float* __restrict__ g1_w2,  const float* __restrict__ g1_b2,
    const float* __restrict__ g2_w2,  const float* __restrict__ g2_b2,
    float* __restrict__ memb)         // NB x 256, updated in place
{
  __shared__ float As[3][16][64];
  __shared__ float Ws[3][16][64];
  const int tid = threadIdx.x;
  const int tx = tid & 15, ty = tid >> 4;
  const int m0 = blockIdx.x * 64, j0 = blockIdx.y * 64;
  const int lr = tid >> 2, lk = (tid & 3) << 2;

  float aC[4][4], aG1[4][4], aG2[4][4];
  #pragma unroll
  for (int i = 0; i < 4; i++)
    #pragma unroll
    for (int j = 0; j < 4; j++) { aC[i][j] = 0.f; aG1[i][j] = 0.f; aG2[i][j] = 0.f; }

  const float* Wsel[3] = { att2_w2, g1_w2, g2_w2 };

  for (int k0 = 0; k0 < 512; k0 += 16) {
    #pragma unroll
    for (int s = 0; s < 3; s++) {
      float4 av = *(const float4*)(z3 + (size_t)(m0 + lr) * 1536 + s * 512 + k0 + lk);
      float4 wv = *(const float4*)(Wsel[s] + (size_t)(j0 + lr) * 512 + k0 + lk);
      As[s][lk + 0][lr] = av.x; As[s][lk + 1][lr] = av.y;
      As[s][lk + 2][lr] = av.z; As[s][lk + 3][lr] = av.w;
      Ws[s][lk + 0][lr] = wv.x; Ws[s][lk + 1][lr] = wv.y;
      Ws[s][lk + 2][lr] = wv.z; Ws[s][lk + 3][lr] = wv.w;
    }
    __syncthreads();
    #pragma unroll
    for (int kk = 0; kk < 16; kk++) {
      float4 a0 = *(const float4*)&As[0][kk][ty * 4];
      float4 b0 = *(const float4*)&Ws[0][kk][tx * 4];
      float4 a1 = *(const float4*)&As[1][kk][ty * 4];
      float4 b1 = *(const float4*)&Ws[1][kk][tx * 4];
      float4 a2 = *(const float4*)&As[2][kk][ty * 4];
      float4 b2 = *(const float4*)&Ws[2][kk][tx * 4];
      aC[0][0] += a0.x * b0.x; aC[0][1] += a0.x * b0.y; aC[0][2] += a0.x * b0.z; aC[0][3] += a0.x * b0.w;
      aC[1][0] += a0.y * b0.x; aC[1][1] += a0.y * b0.y; aC[1][2] += a0.y * b0.z; aC[1][3] += a0.y * b0.w;
      aC[2][0] += a0.z * b0.x; aC[2][1] += a0.z * b0.y; aC[2][2] += a0.z * b0.z; aC[2][3] += a0.z * b0.w;
      aC[3][0] += a0.w * b0.x; aC[3][1] += a0.w * b0.y; aC[3][2] += a0.w * b0.z; aC[3][3] += a0.w * b0.w;
      aG1[0][0] += a1.x * b1.x; aG1[0][1] += a1.x * b1.y; aG1[0][2] += a1.x * b1.z; aG1[0][3] += a1.x * b1.w;
      aG1[1][0] += a1.y * b1.x; aG1[1][1] += a1.y * b1.y; aG1[1][2] += a1.y * b1.z; aG1[1][3] += a1.y * b1.w;
      aG1[2][0] += a1.z * b1.x; aG1[2][1] += a1.z * b1.y; aG1[2][2] += a1.z * b1.z; aG1[2][3] += a1.z * b1.w;
      aG1[3][0] += a1.w * b1.x; aG1[3][1] += a1.w * b1.y; aG1[3][2] += a1.w * b1.z; aG1[3][3] += a1.w * b1.w;
      aG2[0][0] += a2.x * b2.x; aG2[0][1] += a2.x * b2.y; aG2[0][2] += a2.x * b2.z; aG2[0][3] += a2.x * b2.w;
      aG2[1][0] += a2.y * b2.x; aG2[1][1] += a2.y * b2.y; aG2[1][2] += a2.y * b2.z; aG2[1][3] += a2.y * b2.w;
      aG2[2][0] += a2.z * b2.x; aG2[2][1] += a2.z * b2.y; aG2[2][2] += a2.z * b2.z; aG2[2][3] += a2.z * b2.w;
      aG2[3][0] += a2.w * b2.x; aG2[3][1] += a2.w * b2.y; aG2[3][2] += a2.w * b2.z; aG2[3][3] += a2.w * b2.w;
    }
    __syncthreads();
  }
  #pragma unroll
  for (int i = 0; i < 4; i++) {
    int m = m0 + ty * 4 + i;
    #pragma unroll
    for (int j = 0; j < 4; j++) {
      int jj = j0 + tx * 4 + j;
      float cHat = tanhf_(aC[i][j] + att2_b2[jj]);
      float g1 = sigmoidf_(aG1[i][j] + g1_b2[jj]);
      float g2 = sigmoidf_(aG2[i][j] + g2_b2[jj]);
      size_t off = (size_t)m * 256 + jj;
      memb[off] = g1 * memb[off] + g2 * cHat;
    }
  }
}

// ------------------------------------------- global max per modality (3 blocks)
__global__ __launch_bounds__(256) void max3_kernel(
    const float* __restrict__ pl, float* __restrict__ maxes)
{
  __shared__ float red[256];
  const int b = blockIdx.x, tid = threadIdx.x;
  float mx = -3.4e38f;
  for (int i = tid; i < NB * 128; i += 256) {
    int n = i >> 7, j = i & 127;
    mx = fmaxf(mx, pl[(size_t)n * 384 + b * 128 + j]);
  }
  red[tid] = mx; __syncthreads();
  for (int s = 128; s > 0; s >>= 1) {
    if (tid < s) red[tid] = fmaxf(red[tid], red[tid + s]);
    __syncthreads();
  }
  if (tid == 0) maxes[b] = red[0];
}

// ----------------------------------------------------- final output per row
__global__ __launch_bounds__(256) void out_kernel(
    const float* __restrict__ pl, const float* __restrict__ maxes,
    const float* __restrict__ memb,
    const float* __restrict__ o_w1, const float* __restrict__ o_b1,
    const float* __restrict__ o_w2, const float* __restrict__ o_b2,
    float* __restrict__ out)
{
  __shared__ float hs[384];
  __shared__ float red[256];
  const int n = blockIdx.x, tid = threadIdx.x;
  float M0 = maxes[0], M1 = maxes[1], M2 = maxes[2];
  for (int idx = tid; idx < 384; idx += 256) {
    float v;
    if (idx < 128) {
      float d0 = pl[(size_t)n * 384 + idx] - M0;
      float d1 = pl[(size_t)n * 384 + 128 + idx] - M1;
      float d2 = pl[(size_t)n * 384 + 256 + idx] - M2;
      v = __expf(d0) * d0 + __expf(d1) * d1 + __expf(d2) * d2;
    } else {
      v = memb[(size_t)n * 256 + idx - 128];
    }
    hs[idx] = v;
  }
  __syncthreads();
  float acc = o_b1[tid];
  const float* wr = o_w1 + (size_t)tid * 384;
  #pragma unroll 4
  for (int k = 0; k < 384; k += 4) {
    float4 w = *(const float4*)(wr + k);
    acc += w.x * hs[k] + w.y * hs[k + 1] + w.z * hs[k + 2] + w.w * hs[k + 3];
  }
  red[tid] = fmaxf(acc, 0.f) * o_w2[tid];
  __syncthreads();
  for (int s = 128; s > 0; s >>= 1) {
    if (tid < s) red[tid] += red[tid + s];
    __syncthreads();
  }
  if (tid == 0) out[n] = red[0] + o_b2[0];
}

// ============================================================ host launcher
extern "C" void kernel_launch(void* const* d_in, const int* in_sizes, int n_in,
                              void* d_out, int out_size, void* d_ws, size_t ws_size,
                              hipStream_t stream)
{
  const float* x      = (const float*)d_in[0];
  const float* Wih_l  = (const float*)d_in[1];
  const float* Whh_l  = (const float*)d_in[2];
  const float* bih_l  = (const float*)d_in[3];
  const float* bhh_l  = (const float*)d_in[4];
  const float* Wih_a  = (const float*)d_in[5];
  const float* Whh_a  = (const float*)d_in[6];
  const float* bih_a  = (const float*)d_in[7];
  const float* bhh_a  = (const float*)d_in[8];
  const float* Wih_v  = (const float*)d_in[9];
  const float* Whh_v  = (const float*)d_in[10];
  const float* bih_v  = (const float*)d_in[11];
  const float* bhh_v  = (const float*)d_in[12];
  const float* att1_w1 = (const float*)d_in[13];
  const float* att1_b1 = (const float*)d_in[14];
  const float* att1_w2 = (const float*)d_in[15];
  const float* att1_b2 = (const float*)d_in[16];
  const float* att2_w1 = (const float*)d_in[17];
  const float* att2_b1 = (const float*)d_in[18];
  const float* att2_w2 = (const float*)d_in[19];
  const float* att2_b2 = (const float*)d_in[20];
  const float* g1_w1  = (const float*)d_in[21];
  const float* g1_b1  = (const float*)d_in[22];
  const float* g1_w2  = (const float*)d_in[23];
  const float* g1_b2  = (const float*)d_in[24];
  const float* g2_w1  = (const float*)d_in[25];
  const float* g2_b1  = (const float*)d_in[26];
  const float* g2_w2  = (const float*)d_in[27];
  const float* g2_b2  = (const float*)d_in[28];
  const float* fl_w   = (const float*)d_in[29];
  const float* fl_b   = (const float*)d_in[30];
  const float* fa_w   = (const float*)d_in[31];
  const float* fa_b   = (const float*)d_in[32];
  const float* fv_w   = (const float*)d_in[33];
  const float* fv_b   = (const float*)d_in[34];
  const float* o_w1   = (const float*)d_in[35];
  const float* o_b1   = (const float*)d_in[36];
  const float* o_w2   = (const float*)d_in[37];
  const float* o_b2   = (const float*)d_in[38];

  float* ws = (float*)d_ws;
  // layout (floats)
  float* HB0   = ws;                 // 512*512  h buffers [l|a|v]
  float* HB1   = ws + 262144;        // 512*512
  float* CB    = ws + 524288;        // 512*512  c buffers [l|a|v]
  float* MEMB  = ws + 786432;        // 512*256
  float* CSTAR = ws + 917504;        // 512*1024
  float* Z1    = ws + 1441792;       // 512*512
  float* LOGB  = ws + 1703936;       // 512*1024
  float* ATTD  = ws + 2228224;       // 512*1024
  float* Z3    = ws + 2752512;       // 512*1536
  float* PL    = ws + 3538944;       // 512*384
  float* MX    = ws + 3735552;       // 3

  float* c_l = CB;
  float* c_a = CB + 131072;
  float* c_v = CB + 196608;

  // zero h0/h1/c/mem = first 917504 floats = 229376 float4
  zero_kernel<<<896, 256, 0, stream>>>((float4*)ws, 229376);

  for (int t = 0; t < TSTEPS; t++) {
    float* hin  = (t & 1) ? HB1 : HB0;
    float* hout = (t & 1) ? HB0 : HB1;
    gates_cell_kernel<<<dim3(8, 16), 256, 0, stream>>>(
        x + (size_t)t * NB * DIN,
        hin, hin + 131072, hin + 196608,
        hout, hout + 131072, hout + 196608,
        c_l, c_a, c_v,
        Wih_l, Whh_l, bih_l, bhh_l,
        Wih_a, Whh_a, bih_a, bhh_a,
        Wih_v, Whh_v, bih_v, bhh_v,
        CSTAR);
    // z1 = relu(cStar @ att1_w1^T + b)  (512x512, K=1024)
    lin_kernel<<<dim3(8, 8), 256, 0, stream>>>(CSTAR, 1024, att1_w1, 1024,
                                               att1_b1, Z1, 512, 1024, 1);
    // logits = z1 @ att1_w2^T + b       (512x1024, K=512)
    lin_kernel<<<dim3(8, 16), 256, 0, stream>>>(Z1, 512, att1_w2, 512,
                                                att1_b2, LOGB, 1024, 512, 0);
    softmax_attend_kernel<<<512, 256, 0, stream>>>(LOGB, CSTAR, ATTD);
    z3_kernel<<<dim3(8, 24), 256, 0, stream>>>(ATTD, MEMB,
                                               att2_w1, att2_b1,
                                               g1_w1, g1_b1,
                                               g2_w1, g2_b1, Z3);
    gmem_kernel<<<dim3(8, 4), 256, 0, stream>>>(Z3,
                                                att2_w2, att2_b2,
                                                g1_w2, g1_b2,
                                                g2_w2, g2_b2, MEMB);
  }

  // final h is in HB0 (t=63 wrote HB0)
  float* h_l = HB0;
  float* h_a = HB0 + 131072;
  float* h_v = HB0 + 196608;

  // p-logits: PL[:,0:128]=h_l@fl_w^T+b, [128:256]=h_a@fa_w^T+b, [256:384]=h_v@fv_w^T+b
  lin_kernel<<<dim3(8, 2), 256, 0, stream>>>(h_l, 256, fl_w, 256, fl_b,
                                             PL, 384, 256, 0);
  lin_kernel<<<dim3(8, 2), 256, 0, stream>>>(h_a, 128, fa_w, 128, fa_b,
                                             PL + 128, 384, 128, 0);
  lin_kernel<<<dim3(8, 2), 256, 0, stream>>>(h_v, 128, fv_w, 128, fv_b,
                                             PL + 256, 384, 128, 0);
  max3_kernel<<<3, 256, 0, stream>>>(PL, MX);
  out_kernel<<<512, 256, 0, stream>>>(PL, MX, MEMB, o_w1, o_b1, o_w2, o_b2,
                                      (float*)d_out);
}

// Round 2
// 5713.650 us; speedup vs baseline: 3.4247x; 3.4247x over previous
//
#include <hip/hip_runtime.h>

// ---------------------------------------------------------------- types
typedef __bf16 bf16_t;
typedef bf16_t bf16x8 __attribute__((ext_vector_type(8)));
typedef bf16_t bf16x4 __attribute__((ext_vector_type(4)));
typedef float  f32x4  __attribute__((ext_vector_type(4)));

#define MFMA16(a,b,c) __builtin_amdgcn_mfma_f32_16x16x32_bf16((a),(b),(c),0,0,0)

// Problem dims
#define TSTEPS 64
#define NB     512
#define DIN    556

// bf16 weight-pool element offsets
#define OFF_WIHP_L 0u         // 1024 x 320
#define OFF_WHH_L  327680u    // 1024 x 256
#define OFF_WIHP_A 589824u    // 512 x 128
#define OFF_WHH_A  655360u    // 512 x 128
#define OFF_WIHP_V 720896u
#define OFF_WHH_V  786432u
#define OFF_ATT1W1 851968u    // 512 x 1024
#define OFF_ATT1W2 1376256u   // 1024 x 512
#define OFF_ATT2W1 1900544u   // 512 x 1024
#define OFF_ATT2W2 2424832u   // 256 x 512
#define OFF_G1W1   2555904u   // 512 x 1280
#define OFF_G1W2   3211264u   // 256 x 512
#define OFF_G2W1   3342336u   // 512 x 1280
#define OFF_G2W2   3997696u   // 256 x 512
#define OFF_FLW    4128768u   // 128 x 256
#define OFF_FAW    4161536u   // 128 x 128
#define OFF_FVW    4177920u   // 128 x 128

#define LDSK 40   // LDS row stride (bf16) for 32-wide k tiles: 80B -> <=2-way conflicts

__device__ __forceinline__ float sigmoidf_(float x) {
  return 1.0f / (1.0f + __expf(-x));
}
__device__ __forceinline__ float tanhf_(float x) {
  x = fminf(fmaxf(x, -15.0f), 15.0f);
  float e = __expf(2.0f * x);
  return (e - 1.0f) / (e + 1.0f);
}

// ---------------------------------------------------------------- zero init
__global__ __launch_bounds__(256) void zero_kernel(float4* p, int n4) {
  int i = blockIdx.x * 256 + threadIdx.x;
  if (i < n4) p[i] = make_float4(0.f, 0.f, 0.f, 0.f);
}

// ---------------------------------------------------- convert+pad weights
// dst[r][k] = k < K ? (bf16)src[r][k] : 0,  dst rows Kpad wide
__global__ __launch_bounds__(256) void cvt_pad_kernel(
    const float* __restrict__ src, bf16_t* __restrict__ dst, int K, int Kpad)
{
  int r = blockIdx.x;
  for (int k = threadIdx.x; k < Kpad; k += 256)
    dst[(size_t)r * Kpad + k] = (k < K) ? (bf16_t)src[(size_t)r * K + k] : (bf16_t)0.f;
}

// ------------------------------------------- split x into per-modality bf16
__global__ __launch_bounds__(256) void cvt_x_kernel(
    const float* __restrict__ x, bf16_t* __restrict__ xl,
    bf16_t* __restrict__ xa, bf16_t* __restrict__ xv)
{
  int r = blockIdx.x;  // 0..T*N-1
  const float* xr = x + (size_t)r * DIN;
  for (int c = threadIdx.x; c < 576; c += 256) {
    if (c < 320) {
      xl[(size_t)r * 320 + c] = (c < 300) ? (bf16_t)xr[c] : (bf16_t)0.f;
    } else if (c < 448) {
      xa[(size_t)r * 128 + (c - 320)] = (bf16_t)xr[300 + (c - 320)];
    } else {
      xv[(size_t)r * 128 + (c - 448)] = (bf16_t)xr[428 + (c - 448)];
    }
  }
}

// --------------------------------------------------------- summed LSTM bias
__global__ __launch_bounds__(256) void bias_sum_kernel(
    const float* __restrict__ bih_l, const float* __restrict__ bhh_l,
    const float* __restrict__ bih_a, const float* __restrict__ bhh_a,
    const float* __restrict__ bih_v, const float* __restrict__ bhh_v,
    float* __restrict__ bsum)
{
  int i = blockIdx.x * 256 + threadIdx.x;
  if (i < 1024)      bsum[i] = bih_l[i] + bhh_l[i];
  else if (i < 1536) bsum[i] = bih_a[i - 1024] + bhh_a[i - 1024];
  else if (i < 2048) bsum[i] = bih_v[i - 1536] + bhh_v[i - 1536];
}

// ------------------------------------------------- fused LSTM gates + cell
// grid (8 m-tiles, 16): y<8 -> l (j0=y*32), y<12 -> a, else v.
// Block: 64 rows x 32 j x 4 gates. Wave g computes gate g (64x32 via 4x2 tiles).
__global__ __launch_bounds__(256) void gates_cell_kernel(
    const bf16_t* __restrict__ xl_t, const bf16_t* __restrict__ xa_t,
    const bf16_t* __restrict__ xv_t,
    const bf16_t* __restrict__ hin,  bf16_t* __restrict__ hout,
    float* __restrict__ cbase,
    const bf16_t* __restrict__ pool, const float* __restrict__ bsum,
    bf16_t* __restrict__ cstar)
{
  __shared__ __align__(16) bf16_t Al[64 * LDSK];
  __shared__ __align__(16) bf16_t Wl[128 * LDSK];
  __shared__ float Gx[4][64][32];

  const int tid = threadIdx.x;
  const int m0 = blockIdx.x * 64;
  const int y  = blockIdx.y;

  const bf16_t *xp, *Wih, *Whh;
  int Kx, Hm, hoff, j0, oldbase, boff;
  if (y < 8) {
    xp = xl_t; Wih = pool + OFF_WIHP_L; Whh = pool + OFF_WHH_L;
    Kx = 320; Hm = 256; hoff = 0; j0 = y * 32; oldbase = 0; boff = 0;
  } else if (y < 12) {
    xp = xa_t; Wih = pool + OFF_WIHP_A; Whh = pool + OFF_WHH_A;
    Kx = 128; Hm = 128; hoff = 131072; j0 = (y - 8) * 32; oldbase = 256; boff = 1024;
  } else {
    xp = xv_t; Wih = pool + OFF_WIHP_V; Whh = pool + OFF_WHH_V;
    Kx = 128; Hm = 128; hoff = 196608; j0 = (y - 12) * 32; oldbase = 384; boff = 1536;
  }

  const int wave = tid >> 6, lane = tid & 63;
  const int lrow = lane & 15, quad = lane >> 4;
  const int srow = tid >> 2, schunk = (tid & 3) * 8;   // A staging: 64 rows x 4 chunks
  const int wrow = tid >> 1, wchunk = (tid & 1) * 16;  // W staging: 128 rows x 2x16

  f32x4 acc[4][2];
  #pragma unroll
  for (int mi = 0; mi < 4; mi++)
    #pragma unroll
    for (int ni = 0; ni < 2; ni++) acc[mi][ni] = f32x4{0.f, 0.f, 0.f, 0.f};

  for (int ph = 0; ph < 2; ph++) {
    const bf16_t* Ab; const bf16_t* Wb; int lda_, ldw_, K_;
    if (ph == 0) { Ab = xp;          lda_ = Kx; K_ = Kx; Wb = Wih; ldw_ = Kx; }
    else         { Ab = hin + hoff;  lda_ = Hm; K_ = Hm; Wb = Whh; ldw_ = Hm; }

    for (int k0 = 0; k0 < K_; k0 += 32) {
      bf16x8 av = *(const bf16x8*)(Ab + (size_t)(m0 + srow) * lda_ + k0 + schunk);
      int g = wrow >> 5, jr = wrow & 31;
      const bf16_t* wsrc = Wb + (size_t)(g * Hm + j0 + jr) * ldw_ + k0 + wchunk;
      bf16x8 wv0 = *(const bf16x8*)(wsrc);
      bf16x8 wv1 = *(const bf16x8*)(wsrc + 8);
      *(bf16x8*)(Al + srow * LDSK + schunk) = av;
      *(bf16x8*)(Wl + wrow * LDSK + wchunk) = wv0;
      *(bf16x8*)(Wl + wrow * LDSK + wchunk + 8) = wv1;
      __syncthreads();
      bf16x8 afr[4], bfr[2];
      #pragma unroll
      for (int mi = 0; mi < 4; mi++)
        afr[mi] = *(const bf16x8*)(Al + (mi * 16 + lrow) * LDSK + quad * 8);
      #pragma unroll
      for (int ni = 0; ni < 2; ni++)
        bfr[ni] = *(const bf16x8*)(Wl + (wave * 32 + ni * 16 + lrow) * LDSK + quad * 8);
      #pragma unroll
      for (int mi = 0; mi < 4; mi++)
        #pragma unroll
        for (int ni = 0; ni < 2; ni++)
          acc[mi][ni] = MFMA16(afr[mi], bfr[ni], acc[mi][ni]);
      __syncthreads();
    }
  }

  // write biased gates to LDS (wave g owns gate g)
  #pragma unroll
  for (int mi = 0; mi < 4; mi++)
    #pragma unroll
    for (int ni = 0; ni < 2; ni++) {
      int col = ni * 16 + lrow;
      float bv = bsum[boff + wave * Hm + j0 + col];
      #pragma unroll
      for (int r = 0; r < 4; r++) {
        Gx[wave][mi * 16 + quad * 4 + r][col] = acc[mi][ni][r] + bv;
      }
    }
  __syncthreads();

  // cell update: each thread 8 elements (m=tid>>2, j=(tid&3)*8..+7)
  float* cbuf = cbase + hoff;
  int m = tid >> 2, jb = (tid & 3) * 8;
  #pragma unroll
  for (int i = 0; i < 8; i++) {
    int j = jb + i;
    float gi = Gx[0][m][j], gf = Gx[1][m][j], gg = Gx[2][m][j], go = Gx[3][m][j];
    size_t off = (size_t)(m0 + m) * Hm + (j0 + j);
    float c_old = cbuf[off];
    float c2 = sigmoidf_(gf) * c_old + sigmoidf_(gi) * tanhf_(gg);
    float h2 = sigmoidf_(go) * tanhf_(c2);
    cbuf[off] = c2;
    hout[hoff + off] = (bf16_t)h2;
    size_t cs = (size_t)(m0 + m) * 1024 + oldbase + (j0 + j);
    cstar[cs] = (bf16_t)c_old;
    cstar[cs + 512] = (bf16_t)c2;
  }
}

// ---------------------------------------------------- generic MFMA lin
// C = act(A_bf16 @ W_bf16^T + bias); 64x64 tile/block; K multiple of 32.
__global__ __launch_bounds__(256) void mfma_lin_kernel(
    const bf16_t* __restrict__ A, int lda,
    const bf16_t* __restrict__ W, int ldw,
    const float* __restrict__ bias,
    bf16_t* __restrict__ Cb, float* __restrict__ Cf, int ldc,
    int K, int act)
{
  __shared__ __align__(16) bf16_t Al[64 * LDSK];
  __shared__ __align__(16) bf16_t Wl[64 * LDSK];
  const int tid = threadIdx.x;
  const int m0 = blockIdx.x * 64, n0 = blockIdx.y * 64;
  const int wave = tid >> 6, lane = tid & 63;
  const int wm = (wave >> 1) * 32, wn = (wave & 1) * 32;
  const int lrow = lane & 15, quad = lane >> 4;
  const int srow = tid >> 2, schunk = (tid & 3) * 8;

  f32x4 acc[2][2];
  #pragma unroll
  for (int mi = 0; mi < 2; mi++)
    #pragma unroll
    for (int ni = 0; ni < 2; ni++) acc[mi][ni] = f32x4{0.f, 0.f, 0.f, 0.f};

  for (int k0 = 0; k0 < K; k0 += 32) {
    bf16x8 av = *(const bf16x8*)(A + (size_t)(m0 + srow) * lda + k0 + schunk);
    bf16x8 wv = *(const bf16x8*)(W + (size_t)(n0 + srow) * ldw + k0 + schunk);
    *(bf16x8*)(Al + srow * LDSK + schunk) = av;
    *(bf16x8*)(Wl + srow * LDSK + schunk) = wv;
    __syncthreads();
    bf16x8 a0 = *(const bf16x8*)(Al + (wm + lrow) * LDSK + quad * 8);
    bf16x8 a1 = *(const bf16x8*)(Al + (wm + 16 + lrow) * LDSK + quad * 8);
    bf16x8 b0 = *(const bf16x8*)(Wl + (wn + lrow) * LDSK + quad * 8);
    bf16x8 b1 = *(const bf16x8*)(Wl + (wn + 16 + lrow) * LDSK + quad * 8);
    acc[0][0] = MFMA16(a0, b0, acc[0][0]);
    acc[0][1] = MFMA16(a0, b1, acc[0][1]);
    acc[1][0] = MFMA16(a1, b0, acc[1][0]);
    acc[1][1] = MFMA16(a1, b1, acc[1][1]);
    __syncthreads();
  }
  #pragma unroll
  for (int mi = 0; mi < 2; mi++)
    #pragma unroll
    for (int ni = 0; ni < 2; ni++) {
      int row0 = m0 + wm + mi * 16 + quad * 4;
      int col = n0 + wn + ni * 16 + lrow;
      float bv = bias[col];
      #pragma unroll
      for (int r = 0; r < 4; r++) {
        float v = acc[mi][ni][r] + bv;
        if (act == 1) v = fmaxf(v, 0.f);
        size_t off = (size_t)(row0 + r) * ldc + col;
        if (Cb) Cb[off] = (bf16_t)v;
        if (Cf) Cf[off] = v;
      }
    }
}

// ---------------------------------------- softmax over 1024 + attended
__global__ __launch_bounds__(256) void softmax_attend_kernel(
    const float* __restrict__ logits, const bf16_t* __restrict__ cstar,
    bf16_t* __restrict__ attd)
{
  __shared__ float red[256];
  const int n = blockIdx.x, tid = threadIdx.x;
  float4 v = *(const float4*)(logits + (size_t)n * 1024 + tid * 4);
  float mx = fmaxf(fmaxf(v.x, v.y), fmaxf(v.z, v.w));
  red[tid] = mx; __syncthreads();
  for (int s = 128; s > 0; s >>= 1) {
    if (tid < s) red[tid] = fmaxf(red[tid], red[tid + s]);
    __syncthreads();
  }
  mx = red[0]; __syncthreads();
  float e0 = __expf(v.x - mx), e1 = __expf(v.y - mx);
  float e2 = __expf(v.z - mx), e3 = __expf(v.w - mx);
  red[tid] = e0 + e1 + e2 + e3; __syncthreads();
  for (int s = 128; s > 0; s >>= 1) {
    if (tid < s) red[tid] += red[tid + s];
    __syncthreads();
  }
  float inv = 1.0f / red[0];
  bf16x4 c4 = *(const bf16x4*)(cstar + (size_t)n * 1024 + tid * 4);
  bf16x4 o;
  o[0] = (bf16_t)(e0 * inv * (float)c4[0]);
  o[1] = (bf16_t)(e1 * inv * (float)c4[1]);
  o[2] = (bf16_t)(e2 * inv * (float)c4[2]);
  o[3] = (bf16_t)(e3 * inv * (float)c4[3]);
  *(bf16x4*)(attd + (size_t)n * 1024 + tid * 4) = o;
}

// ------------------------- merged z2|zg1|zg2 = relu([attended|mem] @ W^T + b)
// grid (8, 24): y<8 att2 (K=1024), y<16 g1 (K=1280), else g2 (K=1280)
__global__ __launch_bounds__(256) void z3_kernel(
    const bf16_t* __restrict__ attd, const bf16_t* __restrict__ membf,
    const bf16_t* __restrict__ pool,
    const float* __restrict__ att2_b1, const float* __restrict__ g1_b1,
    const float* __restrict__ g2_b1,
    bf16_t* __restrict__ z3)
{
  __shared__ __align__(16) bf16_t Al[64 * LDSK];
  __shared__ __align__(16) bf16_t Wl[64 * LDSK];
  const int tid = threadIdx.x;
  const int m0 = blockIdx.x * 64, n0 = blockIdx.y * 64;
  const int wave = tid >> 6, lane = tid & 63;
  const int wm = (wave >> 1) * 32, wn = (wave & 1) * 32;
  const int lrow = lane & 15, quad = lane >> 4;
  const int srow = tid >> 2, schunk = (tid & 3) * 8;

  const bf16_t* W; const float* b; int K, nloc;
  if (n0 < 512)       { W = pool + OFF_ATT2W1; b = att2_b1; K = 1024; nloc = n0; }
  else if (n0 < 1024) { W = pool + OFF_G1W1;  b = g1_b1;  K = 1280; nloc = n0 - 512; }
  else                { W = pool + OFF_G2W1;  b = g2_b1;  K = 1280; nloc = n0 - 1024; }

  f32x4 acc[2][2];
  #pragma unroll
  for (int mi = 0; mi < 2; mi++)
    #pragma unroll
    for (int ni = 0; ni < 2; ni++) acc[mi][ni] = f32x4{0.f, 0.f, 0.f, 0.f};

  for (int k0 = 0; k0 < K; k0 += 32) {
    bf16x8 av;
    if (k0 < 1024)
      av = *(const bf16x8*)(attd + (size_t)(m0 + srow) * 1024 + k0 + schunk);
    else
      av = *(const bf16x8*)(membf + (size_t)(m0 + srow) * 256 + (k0 - 1024) + schunk);
    bf16x8 wv = *(const bf16x8*)(W + (size_t)(nloc + srow) * K + k0 + schunk);
    *(bf16x8*)(Al + srow * LDSK + schunk) = av;
    *(bf16x8*)(Wl + srow * LDSK + schunk) = wv;
    __syncthreads();
    bf16x8 a0 = *(const bf16x8*)(Al + (wm + lrow) * LDSK + quad * 8);
    bf16x8 a1 = *(const bf16x8*)(Al + (wm + 16 + lrow) * LDSK + quad * 8);
    bf16x8 b0 = *(const bf16x8*)(Wl + (wn + lrow) * LDSK + quad * 8);
    bf16x8 b1 = *(const bf16x8*)(Wl + (wn + 16 + lrow) * LDSK + quad * 8);
    acc[0][0] = MFMA16(a0, b0, acc[0][0]);
    acc[0][1] = MFMA16(a0, b1, acc[0][1]);
    acc[1][0] = MFMA16(a1, b0, acc[1][0]);
    acc[1][1] = MFMA16(a1, b1, acc[1][1]);
    __syncthreads();
  }
  #pragma unroll
  for (int mi = 0; mi < 2; mi++)
    #pragma unroll
    for (int ni = 0; ni < 2; ni++) {
      int row0 = m0 + wm + mi * 16 + quad * 4;
      int cloc = wn + ni * 16 + lrow;
      float bv = b[nloc + cloc];
      #pragma unroll
      for (int r = 0; r < 4; r++) {
        float v = fmaxf(acc[mi][ni][r] + bv, 0.f);
        z3[(size_t)(row0 + r) * 1536 + n0 + cloc] = (bf16_t)v;
      }
    }
}

// ------------- merged cHat / gamma1 / gamma2 GEMMs + in-place mem update
// grid (8, 4); 3 GEMMs K=512 from z3 slices; epilogue updates mem.
__global__ __launch_bounds__(256) void gmem_kernel(
    const bf16_t* __restrict__ z3, const bf16_t* __restrict__ pool,
    const float* __restrict__ att2_b2, const float* __restrict__ g1_b2,
    const float* __restrict__ g2_b2,
    float* __restrict__ memf, bf16_t* __restrict__ membf)
{
  __shared__ __align__(16) bf16_t Az[3][64 * LDSK];
  __shared__ __align__(16) bf16_t Wz[3][64 * LDSK];
  const int tid = threadIdx.x;
  const int m0 = blockIdx.x * 64, n0 = blockIdx.y * 64;
  const int wave = tid >> 6, lane = tid & 63;
  const int wm = (wave >> 1) * 32, wn = (wave & 1) * 32;
  const int lrow = lane & 15, quad = lane >> 4;
  const int srow = tid >> 2, schunk = (tid & 3) * 8;

  const bf16_t* Ws[3] = { pool + OFF_ATT2W2, pool + OFF_G1W2, pool + OFF_G2W2 };

  f32x4 acc[3][2][2];
  #pragma unroll
  for (int s = 0; s < 3; s++)
    #pragma unroll
    for (int mi = 0; mi < 2; mi++)
      #pragma unroll
      for (int ni = 0; ni < 2; ni++) acc[s][mi][ni] = f32x4{0.f, 0.f, 0.f, 0.f};

  for (int k0 = 0; k0 < 512; k0 += 32) {
    #pragma unroll
    for (int s = 0; s < 3; s++) {
      bf16x8 av = *(const bf16x8*)(z3 + (size_t)(m0 + srow) * 1536 + s * 512 + k0 + schunk);
      bf16x8 wv = *(const bf16x8*)(Ws[s] + (size_t)(n0 + srow) * 512 + k0 + schunk);
      *(bf16x8*)(Az[s] + srow * LDSK + schunk) = av;
      *(bf16x8*)(Wz[s] + srow * LDSK + schunk) = wv;
    }
    __syncthreads();
    #pragma unroll
    for (int s = 0; s < 3; s++) {
      bf16x8 a0 = *(const bf16x8*)(Az[s] + (wm + lrow) * LDSK + quad * 8);
      bf16x8 a1 = *(const bf16x8*)(Az[s] + (wm + 16 + lrow) * LDSK + quad * 8);
      bf16x8 b0 = *(const bf16x8*)(Wz[s] + (wn + lrow) * LDSK + quad * 8);
      bf16x8 b1 = *(const bf16x8*)(Wz[s] + (wn + 16 + lrow) * LDSK + quad * 8);
      acc[s][0][0] = MFMA16(a0, b0, acc[s][0][0]);
      acc[s][0][1] = MFMA16(a0, b1, acc[s][0][1]);
      acc[s][1][0] = MFMA16(a1, b0, acc[s][1][0]);
      acc[s][1][1] = MFMA16(a1, b1, acc[s][1][1]);
    }
    __syncthreads();
  }
  #pragma unroll
  for (int mi = 0; mi < 2; mi++)
    #pragma unroll
    for (int ni = 0; ni < 2; ni++) {
      int row0 = m0 + wm + mi * 16 + quad * 4;
      int col = n0 + wn + ni * 16 + lrow;
      float bC = att2_b2[col], b1v = g1_b2[col], b2v = g2_b2[col];
      #pragma unroll
      for (int r = 0; r < 4; r++) {
        float cHat = tanhf_(acc[0][mi][ni][r] + bC);
        float g1 = sigmoidf_(acc[1][mi][ni][r] + b1v);
        float g2 = sigmoidf_(acc[2][mi][ni][r] + b2v);
        size_t off = (size_t)(row0 + r) * 256 + col;
        float nm = g1 * memf[off] + g2 * cHat;
        memf[off] = nm;
        membf[off] = (bf16_t)nm;
      }
    }
}

// ------------------------------------------- global max per modality
__global__ __launch_bounds__(256) void max3_kernel(
    const float* __restrict__ pl, float* __restrict__ maxes)
{
  __shared__ float red[256];
  const int b = blockIdx.x, tid = threadIdx.x;
  float mx = -3.4e38f;
  for (int i = tid; i < NB * 128; i += 256) {
    int n = i >> 7, j = i & 127;
    mx = fmaxf(mx, pl[(size_t)n * 384 + b * 128 + j]);
  }
  red[tid] = mx; __syncthreads();
  for (int s = 128; s > 0; s >>= 1) {
    if (tid < s) red[tid] = fmaxf(red[tid], red[tid + s]);
    __syncthreads();
  }
  if (tid == 0) maxes[b] = red[0];
}

// ----------------------------------------------------- final output per row
__global__ __launch_bounds__(256) void out_kernel(
    const float* __restrict__ pl, const float* __restrict__ maxes,
    const float* __restrict__ memb,
    const float* __restrict__ o_w1, const float* __restrict__ o_b1,
    const float* __restrict__ o_w2, const float* __restrict__ o_b2,
    float* __restrict__ out)
{
  __shared__ float hs[384];
  __shared__ float red[256];
  const int n = blockIdx.x, tid = threadIdx.x;
  float M0 = maxes[0], M1 = maxes[1], M2 = maxes[2];
  for (int idx = tid; idx < 384; idx += 256) {
    float v;
    if (idx < 128) {
      float d0 = pl[(size_t)n * 384 + idx] - M0;
      float d1 = pl[(size_t)n * 384 + 128 + idx] - M1;
      float d2 = pl[(size_t)n * 384 + 256 + idx] - M2;
      v = __expf(d0) * d0 + __expf(d1) * d1 + __expf(d2) * d2;
    } else {
      v = memb[(size_t)n * 256 + idx - 128];
    }
    hs[idx] = v;
  }
  __syncthreads();
  float acc = o_b1[tid];
  const float* wr = o_w1 + (size_t)tid * 384;
  #pragma unroll 4
  for (int k = 0; k < 384; k += 4) {
    float4 w = *(const float4*)(wr + k);
    acc += w.x * hs[k] + w.y * hs[k + 1] + w.z * hs[k + 2] + w.w * hs[k + 3];
  }
  red[tid] = fmaxf(acc, 0.f) * o_w2[tid];
  __syncthreads();
  for (int s = 128; s > 0; s >>= 1) {
    if (tid < s) red[tid] += red[tid + s];
    __syncthreads();
  }
  if (tid == 0) out[n] = red[0] + o_b2[0];
}

// ============================================================ host launcher
extern "C" void kernel_launch(void* const* d_in, const int* in_sizes, int n_in,
                              void* d_out, int out_size, void* d_ws, size_t ws_size,
                              hipStream_t stream)
{
  const float* x      = (const float*)d_in[0];
  const float* Wih_l  = (const float*)d_in[1];
  const float* Whh_l  = (const float*)d_in[2];
  const float* bih_l  = (const float*)d_in[3];
  const float* bhh_l  = (const float*)d_in[4];
  const float* Wih_a  = (const float*)d_in[5];
  const float* Whh_a  = (const float*)d_in[6];
  const float* bih_a  = (const float*)d_in[7];
  const float* bhh_a  = (const float*)d_in[8];
  const float* Wih_v  = (const float*)d_in[9];
  const float* Whh_v  = (const float*)d_in[10];
  const float* bih_v  = (const float*)d_in[11];
  const float* bhh_v  = (const float*)d_in[12];
  const float* att1_w1 = (const float*)d_in[13];
  const float* att1_b1 = (const float*)d_in[14];
  const float* att1_w2 = (const float*)d_in[15];
  const float* att1_b2 = (const float*)d_in[16];
  const float* att2_w1 = (const float*)d_in[17];
  const float* att2_b1 = (const float*)d_in[18];
  const float* att2_w2 = (const float*)d_in[19];
  const float* att2_b2 = (const float*)d_in[20];
  const float* g1_w1  = (const float*)d_in[21];
  const float* g1_b1  = (const float*)d_in[22];
  const float* g1_w2  = (const float*)d_in[23];
  const float* g1_b2  = (const float*)d_in[24];
  const float* g2_w1  = (const float*)d_in[25];
  const float* g2_b1  = (const float*)d_in[26];
  const float* g2_w2  = (const float*)d_in[27];
  const float* g2_b2  = (const float*)d_in[28];
  const float* fl_w   = (const float*)d_in[29];
  const float* fl_b   = (const float*)d_in[30];
  const float* fa_w   = (const float*)d_in[31];
  const float* fa_b   = (const float*)d_in[32];
  const float* fv_w   = (const float*)d_in[33];
  const float* fv_b   = (const float*)d_in[34];
  const float* o_w1   = (const float*)d_in[35];
  const float* o_b1   = (const float*)d_in[36];
  const float* o_w2   = (const float*)d_in[37];
  const float* o_b2   = (const float*)d_in[38];

  char* base = (char*)d_ws;
  bf16_t* POOL  = (bf16_t*)(base);                 // 4,194,304 elems = 8 MB
  bf16_t* XL    = (bf16_t*)(base + 8388608);       // 32768 x 320
  bf16_t* XA    = (bf16_t*)(base + 29360128);      // 32768 x 128
  bf16_t* XV    = (bf16_t*)(base + 37748736);      // 32768 x 128
  bf16_t* HB0   = (bf16_t*)(base + 46137344);      // 512 x 512
  bf16_t* HB1   = (bf16_t*)(base + 46661632);
  float*  CBUF  = (float*) (base + 47185920);      // 512 x 512 fp32
  float*  MEMF  = (float*) (base + 48234496);      // 512 x 256 fp32
  bf16_t* MEMBF = (bf16_t*)(base + 48758784);      // 512 x 256
  bf16_t* CSTAR = (bf16_t*)(base + 49020928);      // 512 x 1024
  bf16_t* Z1    = (bf16_t*)(base + 50069504);      // 512 x 512
  float*  LOGB  = (float*) (base + 50593792);      // 512 x 1024 fp32
  bf16_t* ATTD  = (bf16_t*)(base + 52690944);      // 512 x 1024
  bf16_t* Z3    = (bf16_t*)(base + 53739520);      // 512 x 1536
  float*  PL    = (float*) (base + 55312384);      // 512 x 384 fp32
  float*  MX    = (float*) (base + 56098816);      // 3
  float*  BSUM  = (float*) (base + 56099072);      // 2048

  // zero h0/h1/c/mem/membf (contiguous 2,883,584 B = 180,224 float4)
  zero_kernel<<<704, 256, 0, stream>>>((float4*)HB0, 180224);

  // conversions
  cvt_x_kernel<<<TSTEPS * NB, 256, 0, stream>>>(x, XL, XA, XV);
  cvt_pad_kernel<<<1024, 256, 0, stream>>>(Wih_l, POOL + OFF_WIHP_L, 300, 320);
  cvt_pad_kernel<<<1024, 256, 0, stream>>>(Whh_l, POOL + OFF_WHH_L, 256, 256);
  cvt_pad_kernel<<<512, 256, 0, stream>>>(Wih_a, POOL + OFF_WIHP_A, 128, 128);
  cvt_pad_kernel<<<512, 256, 0, stream>>>(Whh_a, POOL + OFF_WHH_A, 128, 128);
  cvt_pad_kernel<<<512, 256, 0, stream>>>(Wih_v, POOL + OFF_WIHP_V, 128, 128);
  cvt_pad_kernel<<<512, 256, 0, stream>>>(Whh_v, POOL + OFF_WHH_V, 128, 128);
  cvt_pad_kernel<<<512, 256, 0, stream>>>(att1_w1, POOL + OFF_ATT1W1, 1024, 1024);
  cvt_pad_kernel<<<1024, 256, 0, stream>>>(att1_w2, POOL + OFF_ATT1W2, 512, 512);
  cvt_pad_kernel<<<512, 256, 0, stream>>>(att2_w1, POOL + OFF_ATT2W1, 1024, 1024);
  cvt_pad_kernel<<<256, 256, 0, stream>>>(att2_w2, POOL + OFF_ATT2W2, 512, 512);
  cvt_pad_kernel<<<512, 256, 0, stream>>>(g1_w1, POOL + OFF_G1W1, 1280, 1280);
  cvt_pad_kernel<<<256, 256, 0, stream>>>(g1_w2, POOL + OFF_G1W2, 512, 512);
  cvt_pad_kernel<<<512, 256, 0, stream>>>(g2_w1, POOL + OFF_G2W1, 1280, 1280);
  cvt_pad_kernel<<<256, 256, 0, stream>>>(g2_w2, POOL + OFF_G2W2, 512, 512);
  cvt_pad_kernel<<<128, 256, 0, stream>>>(fl_w, POOL + OFF_FLW, 256, 256);
  cvt_pad_kernel<<<128, 256, 0, stream>>>(fa_w, POOL + OFF_FAW, 128, 128);
  cvt_pad_kernel<<<128, 256, 0, stream>>>(fv_w, POOL + OFF_FVW, 128, 128);
  bias_sum_kernel<<<8, 256, 0, stream>>>(bih_l, bhh_l, bih_a, bhh_a, bih_v, bhh_v, BSUM);

  for (int t = 0; t < TSTEPS; t++) {
    bf16_t* hin  = (t & 1) ? HB1 : HB0;
    bf16_t* hout = (t & 1) ? HB0 : HB1;
    gates_cell_kernel<<<dim3(8, 16), 256, 0, stream>>>(
        XL + (size_t)t * NB * 320, XA + (size_t)t * NB * 128,
        XV + (size_t)t * NB * 128,
        hin, hout, CBUF, POOL, BSUM, CSTAR);
    // z1 = relu(cStar @ att1_w1^T + b)
    mfma_lin_kernel<<<dim3(8, 8), 256, 0, stream>>>(
        CSTAR, 1024, POOL + OFF_ATT1W1, 1024, att1_b1,
        Z1, (float*)nullptr, 512, 1024, 1);
    // logits = z1 @ att1_w2^T + b (fp32 out)
    mfma_lin_kernel<<<dim3(8, 16), 256, 0, stream>>>(
        Z1, 512, POOL + OFF_ATT1W2, 512, att1_b2,
        (bf16_t*)nullptr, LOGB, 1024, 512, 0);
    softmax_attend_kernel<<<512, 256, 0, stream>>>(LOGB, CSTAR, ATTD);
    z3_kernel<<<dim3(8, 24), 256, 0, stream>>>(ATTD, MEMBF, POOL,
                                               att2_b1, g1_b1, g2_b1, Z3);
    gmem_kernel<<<dim3(8, 4), 256, 0, stream>>>(Z3, POOL,
                                                att2_b2, g1_b2, g2_b2,
                                                MEMF, MEMBF);
  }

  // final h is in HB0 (t=63 wrote HB0)
  bf16_t* h_l = HB0;
  bf16_t* h_a = HB0 + 131072;
  bf16_t* h_v = HB0 + 196608;

  mfma_lin_kernel<<<dim3(8, 2), 256, 0, stream>>>(
      h_l, 256, POOL + OFF_FLW, 256, fl_b, (bf16_t*)nullptr, PL, 384, 256, 0);
  mfma_lin_kernel<<<dim3(8, 2), 256, 0, stream>>>(
      h_a, 128, POOL + OFF_FAW, 128, fa_b, (bf16_t*)nullptr, PL + 128, 384, 128, 0);
  mfma_lin_kernel<<<dim3(8, 2), 256, 0, stream>>>(
      h_v, 128, POOL + OFF_FVW, 128, fv_b, (bf16_t*)nullptr, PL + 256, 384, 128, 0);
  max3_kernel<<<3, 256, 0, stream>>>(PL, MX);
  out_kernel<<<512, 256, 0, stream>>>(PL, MX, MEMF, o_w1, o_b1, o_w2, o_b2,
                                      (float*)d_out);
}